// Round 1
// baseline (494.466 us; speedup 1.0000x reference)
//
#include <hip/hip_runtime.h>
#include <hip/hip_bf16.h>

#define NB   4
#define NC   256
#define NPOS 4096
#define NDQK 32

typedef __bf16 bf16x8 __attribute__((ext_vector_type(8)));
typedef float  f32x4  __attribute__((ext_vector_type(4)));

// ---------------- projection q/k: [32x256] x [256 x 64pos] per block ----------------
__global__ __launch_bounds__(256) void proj_qk_kernel(
    const float* __restrict__ x,
    const float* __restrict__ Wq, const float* __restrict__ bq,
    const float* __restrict__ Wk, const float* __restrict__ bk,
    __hip_bfloat16* __restrict__ Qb, __hip_bfloat16* __restrict__ Kb)
{
    __shared__ float xl[NC * 64];
    const int tx = threadIdx.x;          // 0..63  position within tile
    const int ty = threadIdx.y;          // 0..3
    const int t  = ty * 64 + tx;
    const int b  = blockIdx.x >> 6;
    const int n0 = (blockIdx.x & 63) << 6;

    // stage x tile [256 c][64 n] into LDS (coalesced float4)
    #pragma unroll
    for (int it = 0; it < 16; ++it) {
        int u = it * 256 + t;            // float4 index, 4096 total
        int c = u >> 4, n4 = u & 15;
        const float4 v = *reinterpret_cast<const float4*>(
            x + ((size_t)(b * NC + c)) * NPOS + n0 + n4 * 4);
        *reinterpret_cast<float4*>(xl + c * 64 + n4 * 4) = v;
    }
    __syncthreads();

    const float* __restrict__ W   = blockIdx.y ? Wk : Wq;
    const float* __restrict__ bs  = blockIdx.y ? bk : bq;
    __hip_bfloat16* __restrict__ dst = blockIdx.y ? Kb : Qb;

    float acc[8];
    #pragma unroll
    for (int oo = 0; oo < 8; ++oo) acc[oo] = bs[oo * 4 + ty];

    for (int c8 = 0; c8 < 32; ++c8) {
        float xr[8];
        #pragma unroll
        for (int cc = 0; cc < 8; ++cc) xr[cc] = xl[(c8 * 8 + cc) * 64 + tx];
        #pragma unroll
        for (int oo = 0; oo < 8; ++oo) {
            const int o = oo * 4 + ty;              // wave-uniform -> s_loads for W
            #pragma unroll
            for (int cc = 0; cc < 8; ++cc)
                acc[oo] += W[o * NC + c8 * 8 + cc] * xr[cc];
        }
    }
    // Q/K layout: [b][n][d] bf16 (position-major rows of 32 dims)
    #pragma unroll
    for (int oo = 0; oo < 8; ++oo) {
        const int o = oo * 4 + ty;
        dst[((size_t)(b * NPOS + n0 + tx)) * NDQK + o] = __float2bfloat16(acc[oo]);
    }
}

// ---------------- projection v: 64 output rows per block.y ----------------
__global__ __launch_bounds__(256) void proj_v_kernel(
    const float* __restrict__ x,
    const float* __restrict__ Wv, const float* __restrict__ bv,
    __hip_bfloat16* __restrict__ Vb)
{
    __shared__ float xl[NC * 64];
    const int tx = threadIdx.x;
    const int ty = threadIdx.y;
    const int t  = ty * 64 + tx;
    const int b  = blockIdx.x >> 6;
    const int n0 = (blockIdx.x & 63) << 6;
    const int gy = blockIdx.y;           // 0..3 -> 64 output channels each

    #pragma unroll
    for (int it = 0; it < 16; ++it) {
        int u = it * 256 + t;
        int c = u >> 4, n4 = u & 15;
        const float4 v = *reinterpret_cast<const float4*>(
            x + ((size_t)(b * NC + c)) * NPOS + n0 + n4 * 4);
        *reinterpret_cast<float4*>(xl + c * 64 + n4 * 4) = v;
    }
    __syncthreads();

    float acc[16];
    #pragma unroll
    for (int oo = 0; oo < 16; ++oo) acc[oo] = bv[gy * 64 + oo * 4 + ty];

    for (int c8 = 0; c8 < 32; ++c8) {
        float xr[8];
        #pragma unroll
        for (int cc = 0; cc < 8; ++cc) xr[cc] = xl[(c8 * 8 + cc) * 64 + tx];
        #pragma unroll
        for (int oo = 0; oo < 16; ++oo) {
            const int o = gy * 64 + oo * 4 + ty;
            #pragma unroll
            for (int cc = 0; cc < 8; ++cc)
                acc[oo] += Wv[(size_t)o * NC + c8 * 8 + cc] * xr[cc];
        }
    }
    // V layout: [b][c][n] bf16 (channel rows, coalesced in n)
    #pragma unroll
    for (int oo = 0; oo < 16; ++oo) {
        const int o = gy * 64 + oo * 4 + ty;
        Vb[((size_t)(b * NC + o)) * NPOS + n0 + tx] = __float2bfloat16(acc[oo]);
    }
}

// ---------------- fused flash attention + residual ----------------
// grid: 256 blocks, bid = qb*4 + b  (keeps one batch per XCD under %8 round-robin)
// block: 256 threads = 4 waves; wave handles 16 queries.
__global__ __launch_bounds__(256) void attn_kernel(
    const __hip_bfloat16* __restrict__ Qb,
    const __hip_bfloat16* __restrict__ Kb,
    const __hip_bfloat16* __restrict__ Vb,
    const float* __restrict__ x,
    const float* __restrict__ gamma,
    float* __restrict__ out)
{
    __shared__ float ol[NC * 64];        // 64 KB: output tile transpose buffer
    const int t    = threadIdx.x;
    const int lane = t & 63;
    const int w    = t >> 6;
    const int b    = blockIdx.x & 3;
    const int qb   = blockIdx.x >> 2;    // 0..63
    const int q0   = qb * 64 + w * 16;
    const int qr   = lane & 15;          // query index within 16 (MFMA col)
    const int g    = lane >> 4;          // k-group 0..3

    const __bf16* __restrict__ Qp = reinterpret_cast<const __bf16*>(Qb);
    const __bf16* __restrict__ Kp = reinterpret_cast<const __bf16*>(Kb) + (size_t)b * NPOS * NDQK;
    const __bf16* __restrict__ Vp = reinterpret_cast<const __bf16*>(Vb) + (size_t)b * NC * NPOS;

    // Q fragment: B-operand of swapped QK^T: B[d][q], lane holds Q[q=qr][d=g*8+i]
    const bf16x8 qf = *reinterpret_cast<const bf16x8*>(
        Qp + ((size_t)(b * NPOS + q0 + qr)) * NDQK + g * 8);

    f32x4 acc[16];
    #pragma unroll
    for (int cb = 0; cb < 16; ++cb) acc[cb] = f32x4{0.f, 0.f, 0.f, 0.f};
    float m_run = -3.0e38f;
    float l_run = 0.f;

    // j-remap so that P lands lane-local in PV A-fragment layout:
    // K-frag sub-tile s row m  ->  global j = j0 + 8*(m>>2) + 4*s + (m&3)
    const int roff = 8 * (qr >> 2) + (qr & 3);

    for (int jt = 0; jt < NPOS / 32; ++jt) {
        const int j0 = jt * 32;
        const bf16x8 kf0 = *reinterpret_cast<const bf16x8*>(
            Kp + (size_t)(j0 + roff) * NDQK + g * 8);
        const bf16x8 kf1 = *reinterpret_cast<const bf16x8*>(
            Kp + (size_t)(j0 + roff + 4) * NDQK + g * 8);

        // prefetch V fragments for this tile (independent of softmax VALU)
        bf16x8 vf[16];
        #pragma unroll
        for (int cb = 0; cb < 16; ++cb)
            vf[cb] = *reinterpret_cast<const bf16x8*>(
                Vp + (size_t)(cb * 16 + qr) * NPOS + j0 + g * 8);

        const f32x4 zero = {0.f, 0.f, 0.f, 0.f};
        // S^T = K * Q^T : D[m=j][n=q]; lane holds q=qr, j = j0 + 8g + 4s + r
        f32x4 s0 = __builtin_amdgcn_mfma_f32_16x16x32_bf16(kf0, qf, zero, 0, 0, 0);
        f32x4 s1 = __builtin_amdgcn_mfma_f32_16x16x32_bf16(kf1, qf, zero, 0, 0, 0);

        float tm = fmaxf(fmaxf(fmaxf(s0[0], s0[1]), fmaxf(s0[2], s0[3])),
                         fmaxf(fmaxf(s1[0], s1[1]), fmaxf(s1[2], s1[3])));
        tm = fmaxf(tm, __shfl_xor(tm, 16));
        tm = fmaxf(tm, __shfl_xor(tm, 32));

        float p[8];
        if (__all(tm <= m_run + 8.f)) {
            // defer-max: keep old max, skip accumulator rescale (p <= e^8)
            #pragma unroll
            for (int i = 0; i < 4; ++i) p[i]     = __expf(s0[i] - m_run);
            #pragma unroll
            for (int i = 0; i < 4; ++i) p[i + 4] = __expf(s1[i] - m_run);
            float rs = ((p[0] + p[1]) + (p[2] + p[3])) + ((p[4] + p[5]) + (p[6] + p[7]));
            rs += __shfl_xor(rs, 16);
            rs += __shfl_xor(rs, 32);
            l_run += rs;
        } else {
            const float m_new = fmaxf(m_run, tm);
            const float sc = __expf(m_run - m_new);
            #pragma unroll
            for (int i = 0; i < 4; ++i) p[i]     = __expf(s0[i] - m_new);
            #pragma unroll
            for (int i = 0; i < 4; ++i) p[i + 4] = __expf(s1[i] - m_new);
            float rs = ((p[0] + p[1]) + (p[2] + p[3])) + ((p[4] + p[5]) + (p[6] + p[7]));
            rs += __shfl_xor(rs, 16);
            rs += __shfl_xor(rs, 32);
            l_run = l_run * sc + rs;
            m_run = m_new;
            float scr[4];
            #pragma unroll
            for (int r = 0; r < 4; ++r) scr[r] = __shfl(sc, g * 4 + r);
            #pragma unroll
            for (int cb = 0; cb < 16; ++cb) {
                #pragma unroll
                for (int r = 0; r < 4; ++r) acc[cb][r] *= scr[r];
            }
        }

        // p -> bf16 A-fragment: lane holds P[q=qr][j = j0 + 8g + i], i = 4s + r
        bf16x8 pa;
        #pragma unroll
        for (int i = 0; i < 8; ++i) pa[i] = (__bf16)p[i];

        // PV: O^T[q][c] += P[16x32] * V^T[32x16] per 16-channel block
        #pragma unroll
        for (int cb = 0; cb < 16; ++cb)
            acc[cb] = __builtin_amdgcn_mfma_f32_16x16x32_bf16(pa, vf[cb], acc[cb], 0, 0, 0);
    }

    // epilogue: divide by l, transpose through LDS, fuse residual + gamma
    float li[4];
    #pragma unroll
    for (int r = 0; r < 4; ++r) li[r] = 1.f / __shfl(l_run, g * 4 + r);

    #pragma unroll
    for (int cb = 0; cb < 16; ++cb) {
        const int c = cb * 16 + qr;
        #pragma unroll
        for (int r = 0; r < 4; ++r)
            ol[c * 64 + w * 16 + g * 4 + r] = acc[cb][r] * li[r];
    }
    __syncthreads();

    const float gm = gamma[0];
    #pragma unroll
    for (int pass = 0; pass < 4; ++pass) {
        const int c    = pass * 64 + (t >> 2);
        const int nloc = (t & 3) * 16;
        const size_t gb = ((size_t)(b * NC + c)) * NPOS + qb * 64 + nloc;
        #pragma unroll
        for (int u4 = 0; u4 < 4; ++u4) {
            const float4 xv = *reinterpret_cast<const float4*>(x + gb + u4 * 4);
            const float* op = ol + c * 64 + nloc + u4 * 4;
            float4 r;
            r.x = xv.x + gm * op[0];
            r.y = xv.y + gm * op[1];
            r.z = xv.z + gm * op[2];
            r.w = xv.w + gm * op[3];
            *reinterpret_cast<float4*>(out + gb + u4 * 4) = r;
        }
    }
}

extern "C" void kernel_launch(void* const* d_in, const int* in_sizes, int n_in,
                              void* d_out, int out_size, void* d_ws, size_t ws_size,
                              hipStream_t stream) {
    (void)in_sizes; (void)n_in; (void)out_size; (void)ws_size;
    const float* x     = (const float*)d_in[0];
    const float* Wq    = (const float*)d_in[1];
    const float* bq    = (const float*)d_in[2];
    const float* Wk    = (const float*)d_in[3];
    const float* bk    = (const float*)d_in[4];
    const float* Wv    = (const float*)d_in[5];
    const float* bv    = (const float*)d_in[6];
    const float* gamma = (const float*)d_in[7];
    float* out = (float*)d_out;

    char* ws = (char*)d_ws;
    __hip_bfloat16* Qb = (__hip_bfloat16*)(ws);                    // 1 MB
    __hip_bfloat16* Kb = (__hip_bfloat16*)(ws + (1u << 20));       // 1 MB
    __hip_bfloat16* Vb = (__hip_bfloat16*)(ws + (2u << 20));       // 8 MB

    dim3 blk(64, 4);
    proj_qk_kernel<<<dim3(256, 2), blk, 0, stream>>>(x, Wq, bq, Wk, bk, Qb, Kb);
    proj_v_kernel <<<dim3(256, 4), blk, 0, stream>>>(x, Wv, bv, Vb);
    attn_kernel   <<<256, 256, 0, stream>>>(Qb, Kb, Vb, x, gamma, out);
}

// Round 2
// 181.499 us; speedup vs baseline: 2.7243x; 2.7243x over previous
//
#include <hip/hip_runtime.h>
#include <hip/hip_bf16.h>

#define NB   4
#define NC   256
#define NPOS 4096
#define NDQK 32

typedef __bf16 bf16x8  __attribute__((ext_vector_type(8)));
typedef float  f32x16  __attribute__((ext_vector_type(16)));

// =====================================================================
// Projection kernel: Y[o][n] = sum_c W[o][c] * x[c][n] + b[o], bf16 MFMA.
// Wave-item = (b, ot, nch): ot 0..7 -> Wv rows ot*32 (out V[b][c][n]),
// ot==8 -> Wq (out Q[b][n][d]), ot==9 -> Wk (out K[b][n][d]).
// MFMA 32x32x16: A = W-frag (hoisted), B = x-frag (coalesced fp32 loads).
// =====================================================================
__global__ __launch_bounds__(256) void proj_kernel(
    const float* __restrict__ x,
    const float* __restrict__ Wq, const float* __restrict__ bq,
    const float* __restrict__ Wk, const float* __restrict__ bk,
    const float* __restrict__ Wv, const float* __restrict__ bv,
    __hip_bfloat16* __restrict__ Qb, __hip_bfloat16* __restrict__ Kb,
    __hip_bfloat16* __restrict__ Vb)
{
    const int t   = threadIdx.x;
    const int l   = t & 63;
    const int w   = t >> 6;
    const int hi  = l >> 5;          // which k-half of the fragment
    const int col = l & 31;          // n within 32-tile (B col / D col)
    const int row = l & 31;          // o within 32-tile (A row)

    const int item = blockIdx.x * 4 + w;     // 0..1279
    const int nch  = item & 31;              // 32 n-chunks of 128
    const int rest = item >> 5;              // 0..39
    const int ot   = rest % 10;
    const int b    = rest / 10;

    const float* W;  const float* bs;  int o0;
    if (ot < 8)       { W = Wv; bs = bv; o0 = ot * 32; }
    else if (ot == 8) { W = Wq; bs = bq; o0 = 0; }
    else              { W = Wk; bs = bk; o0 = 0; }

    // hoist W fragments: lane holds W[o0+row][c = kk*16 + 8*hi + i]
    bf16x8 wf[16];
    const float* Wr = W + (size_t)(o0 + row) * NC + 8 * hi;
    #pragma unroll
    for (int kk = 0; kk < 16; ++kk) {
        const float4 a = *reinterpret_cast<const float4*>(Wr + kk * 16);
        const float4 c = *reinterpret_cast<const float4*>(Wr + kk * 16 + 4);
        bf16x8 f;
        f[0] = (__bf16)a.x; f[1] = (__bf16)a.y; f[2] = (__bf16)a.z; f[3] = (__bf16)a.w;
        f[4] = (__bf16)c.x; f[5] = (__bf16)c.y; f[6] = (__bf16)c.z; f[7] = (__bf16)c.w;
        wf[kk] = f;
    }
    // per-reg bias (D row o = (r&3) + 8*(r>>2) + 4*hi)
    float brow[16];
    #pragma unroll
    for (int r = 0; r < 16; ++r)
        brow[r] = bs[o0 + (r & 3) + 8 * (r >> 2) + 4 * hi];

    #pragma unroll 1
    for (int tile = 0; tile < 4; ++tile) {
        const int n0 = nch * 128 + tile * 32;
        f32x16 acc;
        #pragma unroll
        for (int r = 0; r < 16; ++r) acc[r] = 0.f;

        const float* xcol = x + (size_t)b * NC * NPOS + n0 + col;
        #pragma unroll
        for (int kk = 0; kk < 16; ++kk) {
            bf16x8 bf;
            #pragma unroll
            for (int i = 0; i < 8; ++i)
                bf[i] = (__bf16)xcol[(size_t)(kk * 16 + 8 * hi + i) * NPOS];
            acc = __builtin_amdgcn_mfma_f32_32x32x16_bf16(wf[kk], bf, acc, 0, 0, 0);
        }

        if (ot < 8) {
            // V[b][o][n]: per reg, 32 lanes write consecutive n -> coalesced
            #pragma unroll
            for (int r = 0; r < 16; ++r) {
                const int orow = (r & 3) + 8 * (r >> 2) + 4 * hi;
                Vb[((size_t)(b * NC + o0 + orow)) * NPOS + n0 + col] =
                    __float2bfloat16(acc[r] + brow[r]);
            }
        } else {
            __hip_bfloat16* dst = (ot == 8) ? Qb : Kb;
            #pragma unroll
            for (int r = 0; r < 16; ++r) {
                const int orow = (r & 3) + 8 * (r >> 2) + 4 * hi;
                dst[((size_t)(b * NPOS) + n0 + col) * NDQK + orow] =
                    __float2bfloat16(acc[r] + brow[r]);
            }
        }
    }
}

// =====================================================================
// Fused flash attention + residual, 32x32x16 MFMA.
// Wave = 32 queries x 64 channels. Block = 4 waves (same q-tile, 4 ch groups).
// Grid = 512 blocks, bid = qb*4 + b  (each XCD serves exactly one batch's K/V).
//
// Swapped QK^T: S^T[m][q] = K-row(perm(m)) . Q(q); perm swaps bits 2<->3 so
// each lane's 16 S-regs are exactly the PV B-fragment (P[j][q]) in order.
// Softmax is fully lane-local per q (one shfl_xor(32) for max and for sum).
// =====================================================================
__global__ __launch_bounds__(256) void attn_kernel(
    const __hip_bfloat16* __restrict__ Qb,
    const __hip_bfloat16* __restrict__ Kb,
    const __hip_bfloat16* __restrict__ Vb,
    const float* __restrict__ x,
    const float* __restrict__ gamma,
    float* __restrict__ out)
{
    __shared__ float ol[NC * 36];            // stride 36 (16B-aligned, conflict-free)
    const int t   = threadIdx.x;
    const int l   = t & 63;
    const int w   = t >> 6;
    const int hi  = l >> 5;
    const int q   = l & 31;                  // query col / V c-row within 32
    const int b   = blockIdx.x & 3;
    const int qb  = blockIdx.x >> 2;         // 0..127
    const int q0  = qb * 32;
    const int c0w = w * 64;

    const __bf16* Qp = reinterpret_cast<const __bf16*>(Qb) + (size_t)b * NPOS * NDQK;
    const __bf16* Kp = reinterpret_cast<const __bf16*>(Kb) + (size_t)b * NPOS * NDQK;
    const __bf16* Vp = reinterpret_cast<const __bf16*>(Vb) + (size_t)b * NC * NPOS;

    // perm: swap bit2 <-> bit3 of A-row index
    const int perm = (q & 0x13) | ((q & 4) << 1) | ((q & 8) >> 1);

    // Q fragments (B-operand): lane holds Q[q0+q][d = 8*hi + i (+16)]
    const bf16x8 qf0 = *reinterpret_cast<const bf16x8*>(Qp + (size_t)(q0 + q) * NDQK + 8 * hi);
    const bf16x8 qf1 = *reinterpret_cast<const bf16x8*>(Qp + (size_t)(q0 + q) * NDQK + 16 + 8 * hi);

    const __bf16* Kbase = Kp + (size_t)perm * NDQK + 8 * hi;
    const __bf16* V0 = Vp + (size_t)(c0w + q) * NPOS + 8 * hi;
    const __bf16* V1 = V0 + (size_t)32 * NPOS;

    f32x16 acc0, acc1;
    #pragma unroll
    for (int r = 0; r < 16; ++r) { acc0[r] = 0.f; acc1[r] = 0.f; }
    float m_run = -3.0e38f;
    float l_run = 0.f;

    #pragma unroll 1
    for (int jt = 0; jt < NPOS / 32; ++jt) {
        const int j0 = jt * 32;
        // K fragments (A-operand): row m holds K[j0 + perm(m)]
        const bf16x8 kf0 = *reinterpret_cast<const bf16x8*>(Kbase + (size_t)j0 * NDQK);
        const bf16x8 kf1 = *reinterpret_cast<const bf16x8*>(Kbase + (size_t)j0 * NDQK + 16);
        // V fragments (A-operand of PV): rows c, k = j
        const bf16x8 vf00 = *reinterpret_cast<const bf16x8*>(V0 + j0);
        const bf16x8 vf01 = *reinterpret_cast<const bf16x8*>(V0 + j0 + 16);
        const bf16x8 vf10 = *reinterpret_cast<const bf16x8*>(V1 + j0);
        const bf16x8 vf11 = *reinterpret_cast<const bf16x8*>(V1 + j0 + 16);

        f32x16 s;
        #pragma unroll
        for (int r = 0; r < 16; ++r) s[r] = 0.f;
        s = __builtin_amdgcn_mfma_f32_32x32x16_bf16(kf0, qf0, s, 0, 0, 0);
        s = __builtin_amdgcn_mfma_f32_32x32x16_bf16(kf1, qf1, s, 0, 0, 0);

        float tm = s[0];
        #pragma unroll
        for (int r = 1; r < 16; ++r) tm = fmaxf(tm, s[r]);
        tm = fmaxf(tm, __shfl_xor(tm, 32));

        float p[16];
        if (__all(tm <= m_run + 8.f)) {
            // defer-max: skip accumulator rescale (p bounded by e^8)
            #pragma unroll
            for (int r = 0; r < 16; ++r) p[r] = __expf(s[r] - m_run);
        } else {
            const float m_new = fmaxf(m_run, tm);
            const float sc = __expf(m_run - m_new);
            #pragma unroll
            for (int r = 0; r < 16; ++r) p[r] = __expf(s[r] - m_new);
            l_run *= sc;
            #pragma unroll
            for (int r = 0; r < 16; ++r) { acc0[r] *= sc; acc1[r] *= sc; }
            m_run = m_new;
        }
        float rs = 0.f;
        #pragma unroll
        for (int r = 0; r < 16; ++r) rs += p[r];
        rs += __shfl_xor(rs, 32);
        l_run += rs;

        // P fragments (B-operand): pa0 = j-chunk [0,16), pa1 = [16,32)
        bf16x8 pa0, pa1;
        #pragma unroll
        for (int i = 0; i < 8; ++i) { pa0[i] = (__bf16)p[i]; pa1[i] = (__bf16)p[8 + i]; }

        acc0 = __builtin_amdgcn_mfma_f32_32x32x16_bf16(vf00, pa0, acc0, 0, 0, 0);
        acc0 = __builtin_amdgcn_mfma_f32_32x32x16_bf16(vf01, pa1, acc0, 0, 0, 0);
        acc1 = __builtin_amdgcn_mfma_f32_32x32x16_bf16(vf10, pa0, acc1, 0, 0, 0);
        acc1 = __builtin_amdgcn_mfma_f32_32x32x16_bf16(vf11, pa1, acc1, 0, 0, 0);
    }

    const float li = 1.f / l_run;            // lane-local (col q)
    #pragma unroll
    for (int r = 0; r < 16; ++r) {
        const int crow = (r & 3) + 8 * (r >> 2) + 4 * hi;
        ol[(c0w + crow) * 36 + q]      = acc0[r] * li;
        ol[(c0w + 32 + crow) * 36 + q] = acc1[r] * li;
    }
    __syncthreads();

    const float gm = gamma[0];
    #pragma unroll
    for (int pass = 0; pass < 8; ++pass) {
        const int c    = pass * 32 + (t >> 3);
        const int quad = t & 7;
        const size_t gb = ((size_t)(b * NC + c)) * NPOS + q0 + quad * 4;
        const float4 xv = *reinterpret_cast<const float4*>(x + gb);
        const float* op = ol + c * 36 + quad * 4;
        float4 r;
        r.x = xv.x + gm * op[0];
        r.y = xv.y + gm * op[1];
        r.z = xv.z + gm * op[2];
        r.w = xv.w + gm * op[3];
        *reinterpret_cast<float4*>(out + gb) = r;
    }
}

extern "C" void kernel_launch(void* const* d_in, const int* in_sizes, int n_in,
                              void* d_out, int out_size, void* d_ws, size_t ws_size,
                              hipStream_t stream) {
    (void)in_sizes; (void)n_in; (void)out_size; (void)ws_size;
    const float* x     = (const float*)d_in[0];
    const float* Wq    = (const float*)d_in[1];
    const float* bq    = (const float*)d_in[2];
    const float* Wk    = (const float*)d_in[3];
    const float* bk    = (const float*)d_in[4];
    const float* Wv    = (const float*)d_in[5];
    const float* bv    = (const float*)d_in[6];
    const float* gamma = (const float*)d_in[7];
    float* out = (float*)d_out;

    char* ws = (char*)d_ws;
    __hip_bfloat16* Qb = (__hip_bfloat16*)(ws);                    // 1 MB
    __hip_bfloat16* Kb = (__hip_bfloat16*)(ws + (1u << 20));       // 1 MB
    __hip_bfloat16* Vb = (__hip_bfloat16*)(ws + (2u << 20));       // 8 MB

    proj_kernel<<<320, 256, 0, stream>>>(x, Wq, bq, Wk, bk, Wv, bv, Qb, Kb, Vb);
    attn_kernel<<<512, 256, 0, stream>>>(Qb, Kb, Vb, x, gamma, out);
}